// Round 1
// baseline (25381.042 us; speedup 1.0000x reference)
//
#include <hip/hip_runtime.h>
#include <math.h>

// ---------------- constants ----------------
#define DTMEM 0.1f   // DT*TAU_MEM_INV
#define DTSYN 0.2f   // DT*TAU_SYN_INV
#define DTTR  0.02f  // DT*TAU_PRE_INV == DT*TAU_POST_INV

static constexpr int B = 32, T = 32;
static constexpr int HD = 60, H1 = 56, HP = 28, H2 = 24;
static constexpr int LD  = HD*HD;   // 3600
static constexpr int L1N = H1*H1;   // 3136
static constexpr int LP  = HP*HP;   // 784
static constexpr int L2N = H2*H2;   // 576

// float offsets into workspace
static constexpr size_t OW1  = 0;                           // 1500
static constexpr size_t OW2  = OW1 + 1500;                  // 75000
static constexpr size_t OV0  = OW2 + 75000;                 // zero-init region starts here
static constexpr size_t OI0  = OV0  + (size_t)B*30*L1N;
static constexpr size_t OTQ1 = OI0  + (size_t)B*30*L1N;
static constexpr size_t OZ2  = OTQ1 + (size_t)B*30*L1N;
static constexpr size_t OTP1 = OZ2  + (size_t)B*30*L1N;     // [B,60,60] (channel 0 only)
static constexpr size_t OZ0  = OTP1 + (size_t)B*LD;         // [B,60,60] (channel 0 only)
static constexpr size_t OZ3  = OZ0  + (size_t)B*LD;         // [B,30,28,28]
static constexpr size_t OTP2 = OZ3  + (size_t)B*30*LP;
static constexpr size_t OV1  = OTP2 + (size_t)B*30*LP;      // [B,100,24,24]
static constexpr size_t OI1  = OV1  + (size_t)B*100*L2N;
static constexpr size_t OTQ2 = OI1  + (size_t)B*100*L2N;
static constexpr size_t OZ4  = OTQ2 + (size_t)B*100*L2N;
static constexpr size_t OE2P = OZ4  + (size_t)B*100*L2N;    // [100,30,25]
static constexpr size_t OE2M = OE2P + 75000;
static constexpr size_t OP1  = OE2M + 75000;                // stdp1 partials [30][50][4]
static constexpr size_t OG   = OP1  + 6000;                 // [3200]
static constexpr size_t OH   = OG   + 3200;                 // [500]
static constexpr size_t OV2  = OH   + 500;
static constexpr size_t OI2  = OV2  + 500;
static constexpr size_t OVO  = OI2  + 500;
static constexpr size_t OIO  = OVO  + 10;
static constexpr size_t OTOT = OIO  + 10;                   // ~21.39M floats (~85.6 MB)

struct DK { float v[25]; };

// ---------------- K1: DoG conv (channel 0) + tp1 trace update ----------------
__global__ void k_dog(const float* __restrict__ x, const float* __restrict__ b1,
                      const float* __restrict__ b2, float* __restrict__ z0,
                      float* __restrict__ tp1, DK dk, int t) {
    int idx = blockIdx.x*blockDim.x + threadIdx.x;
    if (idx >= B*LD) return;
    int b = idx / LD, r = idx % LD, y = r / HD, xx = r % HD;
    const float* xp = x + ((size_t)t*B + b)*4096;
    float acc = 0.f;
    #pragma unroll
    for (int kh = 0; kh < 5; kh++)
        #pragma unroll
        for (int kw = 0; kw < 5; kw++)
            acc = fmaf(dk.v[kh*5+kw], xp[(y+kh)*64 + xx + kw], acc);
    float zv = acc + (b1[0] - b2[0]);
    z0[idx] = zv;
    float tp = tp1[idx];
    tp1[idx] = tp + DTTR*(zv - tp);
}

// ---------------- K2: conv1 (collapsed channel) + LIF0 + tq1 trace ----------------
__global__ __launch_bounds__(256) void k_conv1lif(
        const float* __restrict__ w1c, const float* __restrict__ z0,
        float* __restrict__ v0, float* __restrict__ i0,
        float* __restrict__ z2, float* __restrict__ tq1) {
    __shared__ float wd[25];
    int bo = blockIdx.y;                 // b*30 + o
    int b = bo / 30, o = bo % 30;
    int tid = threadIdx.x;
    if (tid < 25) wd[tid] = w1c[o*50 + tid] - w1c[o*50 + 25 + tid];
    __syncthreads();
    int l = blockIdx.x*256 + tid;
    if (l >= L1N) return;
    int y = l / H1, xx = l % H1;
    const float* zp = z0 + (size_t)b*LD;
    float acc = 0.f;
    #pragma unroll
    for (int kh = 0; kh < 5; kh++)
        #pragma unroll
        for (int kw = 0; kw < 5; kw++)
            acc = fmaf(wd[kh*5+kw], zp[(y+kh)*HD + xx + kw], acc);
    size_t n = (size_t)bo*L1N + l;
    float v = v0[n], cur = i0[n];
    float vd = v + DTMEM*(cur - v);
    float z = (vd > 15.0f) ? 1.0f : 0.0f;
    v0[n] = (1.0f - z)*vd;
    i0[n] = (cur - DTSYN*cur) + acc;
    z2[n] = z;
    float tq = tq1[n];
    tq1[n] = tq + DTTR*(z - tq);
}

// ---------------- K3: 2x2 maxpool + tp2 trace ----------------
__global__ void k_pool(const float* __restrict__ z2, float* __restrict__ z3,
                       float* __restrict__ tp2) {
    int idx = blockIdx.x*blockDim.x + threadIdx.x;
    if (idx >= B*30*LP) return;
    int bc = idx / LP, r = idx % LP, y = r / HP, xx = r % HP;
    const float* zp = z2 + (size_t)bc*L1N + (2*y)*H1 + 2*xx;
    float m = fmaxf(fmaxf(zp[0], zp[1]), fmaxf(zp[H1], zp[H1+1]));
    z3[idx] = m;
    float tp = tp2[idx];
    tp2[idx] = tp + DTTR*(m - tp);
}

// ---------------- K4a: stdp1 partial sums (channel-0 correlations) ----------------
// grid (4, 30), block 512. partials: [o][q=50][slice=4], q<25 -> plus, q>=25 -> minus
__global__ __launch_bounds__(512) void k_stdp1_part(
        const float* __restrict__ tp1, const float* __restrict__ z2,
        const float* __restrict__ z0, const float* __restrict__ tq1,
        float* __restrict__ part) {
    int o = blockIdx.y, slice = blockIdx.x, tid = threadIdx.x;
    float accp[25], accm[25];
    #pragma unroll
    for (int p = 0; p < 25; p++) { accp[p] = 0.f; accm[p] = 0.f; }
    const int SL = (B*L1N)/4;   // 25088, exactly 49 iters of 512
    for (int i = tid; i < SL; i += 512) {
        int gi = slice*SL + i;
        int b = gi / L1N, l = gi % L1N;
        int y = l / H1, xx = l % H1;
        size_t n = ((size_t)b*30 + o)*L1N + l;
        float z2v = z2[n];
        float tqv = tq1[n];
        const float* tpb = tp1 + (size_t)b*LD;
        const float* z0b = z0 + (size_t)b*LD;
        #pragma unroll
        for (int kh = 0; kh < 5; kh++)
            #pragma unroll
            for (int kw = 0; kw < 5; kw++) {
                int off = (y+kh)*HD + xx + kw;
                accp[kh*5+kw] = fmaf(tpb[off], z2v, accp[kh*5+kw]);
                accm[kh*5+kw] = fmaf(z0b[off], tqv, accm[kh*5+kw]);
            }
    }
    __shared__ float red[8*50];
    int lane = tid & 63, wid = tid >> 6;
    #pragma unroll
    for (int q = 0; q < 50; q++) {
        float v = (q < 25) ? accp[q] : accm[q-25];
        for (int s = 32; s >= 1; s >>= 1) v += __shfl_down(v, s, 64);
        if (lane == 0) red[wid*50 + q] = v;
    }
    __syncthreads();
    if (tid < 50) {
        float s = 0.f;
        #pragma unroll
        for (int w = 0; w < 8; w++) s += red[w*50 + tid];
        part[(o*50 + tid)*4 + slice] = s;
    }
}

// ---------------- K4b: stdp1 apply (signs for on/off channels) ----------------
__global__ void k_stdp1_apply(float* __restrict__ w1c, const float* __restrict__ part) {
    int e = blockIdx.x*blockDim.x + threadIdx.x;
    if (e >= 1500) return;                  // e = o*50 + c*25 + p == flat w1 index
    int o = e / 50, r = e % 50, c = r / 25, p = r % 25;
    float Ep = 0.f, Em = 0.f;
    #pragma unroll
    for (int s = 0; s < 4; s++) {
        Ep += part[(o*50 + p)*4 + s];
        Em += part[(o*50 + 25 + p)*4 + s];
    }
    float sign = (c == 0) ? 1.0f : -1.0f;
    float w = w1c[e];
    float dwp = 0.004f * fmaxf(1.0f - w, 0.0f) * (sign * Ep);
    float dwm = 0.003f * fmaxf(w, 0.0f) * (sign * Em);
    float wn = w + dwp - dwm;
    w1c[e] = fminf(fmaxf(wn, 0.0f), 1.0f);
}

// ---------------- K5: conv2 (j-blocked x4) + LIF1 + tq2 + per-channel spike OR ----------------
// grid (25, B), block 576 (24x24 pixels)
__global__ __launch_bounds__(576) void k_conv2lif(
        const float* __restrict__ w2c, const float* __restrict__ z3,
        float* __restrict__ v1, float* __restrict__ i1,
        float* __restrict__ z4, float* __restrict__ tq2, float* __restrict__ g) {
    __shared__ float wlds[3000];   // [c][tap][jj] -> float4-friendly
    __shared__ float zch[LP];
    __shared__ int sany[4];
    int b = blockIdx.y, j0 = blockIdx.x*4;
    int tid = threadIdx.x;
    if (tid < 4) sany[tid] = 0;
    for (int idx = tid; idx < 3000; idx += 576) {
        int jj = idx & 3, ct = idx >> 2;
        int c = ct / 25, tap = ct % 25;
        wlds[idx] = w2c[((size_t)(j0+jj)*30 + c)*25 + tap];
    }
    int y = tid / H2, xx = tid % H2;
    float acc0 = 0.f, acc1 = 0.f, acc2 = 0.f, acc3 = 0.f;
    for (int c = 0; c < 30; c++) {
        __syncthreads();
        for (int idx = tid; idx < LP; idx += 576)
            zch[idx] = z3[((size_t)b*30 + c)*LP + idx];
        __syncthreads();
        #pragma unroll
        for (int kh = 0; kh < 5; kh++)
            #pragma unroll
            for (int kw = 0; kw < 5; kw++) {
                float zv = zch[(y+kh)*HP + xx + kw];
                const float4 w4 = *(const float4*)&wlds[(c*25 + kh*5 + kw)*4];
                acc0 = fmaf(w4.x, zv, acc0);
                acc1 = fmaf(w4.y, zv, acc1);
                acc2 = fmaf(w4.z, zv, acc2);
                acc3 = fmaf(w4.w, zv, acc3);
            }
    }
    float accs[4] = {acc0, acc1, acc2, acc3};
    #pragma unroll
    for (int jj = 0; jj < 4; jj++) {
        size_t n = ((size_t)b*100 + j0 + jj)*L2N + tid;
        float v = v1[n], cur = i1[n];
        float vd = v + DTMEM*(cur - v);
        float z = (vd > 10.0f) ? 1.0f : 0.0f;
        v1[n] = (1.0f - z)*vd;
        i1[n] = (cur - DTSYN*cur) + 10.0f*accs[jj];
        z4[n] = z;
        float tq = tq2[n];
        tq2[n] = tq + DTTR*(z - tq);
        if (z != 0.0f) atomicOr(&sany[jj], 1);
    }
    __syncthreads();
    if (tid < 4) g[b*100 + j0 + tid] = sany[tid] ? 1.0f : 0.0f;
}

// ---------------- K7: stdp2 weight-gradient correlation (used for both E+ and E-) ----------------
// E[j,c,p] = sum_{b,y,x} pre[b,c,y+kh,x+kw] * post[b,j,y,x]
// grid (50, 30) = (j-group of 2, c), block 576
__global__ __launch_bounds__(576) void k_stdp2_corr(
        const float* __restrict__ pre,    // [B,30,28,28]
        const float* __restrict__ post,   // [B,100,24,24]
        float* __restrict__ E) {          // [100,30,25]
    __shared__ float pch[LP];
    __shared__ float red[9*50];
    int j0 = blockIdx.x*2, c = blockIdx.y;
    int tid = threadIdx.x;
    int y = tid / H2, xx = tid % H2;
    float a0[25], a1[25];
    #pragma unroll
    for (int p = 0; p < 25; p++) { a0[p] = 0.f; a1[p] = 0.f; }
    for (int b = 0; b < B; b++) {
        __syncthreads();
        for (int idx = tid; idx < LP; idx += 576)
            pch[idx] = pre[((size_t)b*30 + c)*LP + idx];
        __syncthreads();
        float za = post[((size_t)b*100 + j0)*L2N + tid];
        float zb = post[((size_t)b*100 + j0 + 1)*L2N + tid];
        #pragma unroll
        for (int kh = 0; kh < 5; kh++)
            #pragma unroll
            for (int kw = 0; kw < 5; kw++) {
                float tv = pch[(y+kh)*HP + xx + kw];
                a0[kh*5+kw] = fmaf(tv, za, a0[kh*5+kw]);
                a1[kh*5+kw] = fmaf(tv, zb, a1[kh*5+kw]);
            }
    }
    int lane = tid & 63, wid = tid >> 6;
    #pragma unroll
    for (int q = 0; q < 50; q++) {
        float v = (q < 25) ? a0[q] : a1[q-25];
        for (int s = 32; s >= 1; s >>= 1) v += __shfl_down(v, s, 64);
        if (lane == 0) red[wid*50 + q] = v;
    }
    __syncthreads();
    if (tid < 50) {
        float s = 0.f;
        #pragma unroll
        for (int w = 0; w < 9; w++) s += red[w*50 + tid];
        int j = j0 + (tid / 25), p = tid % 25;
        E[((size_t)j*30 + c)*25 + p] = s;
    }
}

// ---------------- K8: stdp2 apply ----------------
__global__ void k_stdp2_apply(float* __restrict__ w2c, const float* __restrict__ Ep,
                              const float* __restrict__ Em) {
    int e = blockIdx.x*blockDim.x + threadIdx.x;
    if (e >= 75000) return;        // flat [j][c][p] matches both w2 and E layouts
    float w = w2c[e];
    float dwp = 0.004f * fmaxf(1.0f - w, 0.0f) * Ep[e];
    float dwm = 0.003f * fmaxf(w, 0.0f) * Em[e];
    float wn = w + dwp - dwm;
    w2c[e] = fminf(fmaxf(wn, 0.0f), 1.0f);
}

// ---------------- K6a: fc1 (500x3200, g is binary) ----------------
__global__ void k_fc1(const float* __restrict__ g, const float* __restrict__ fcw,
                      const float* __restrict__ fcb, float* __restrict__ h) {
    int n = blockIdx.x, lane = threadIdx.x;
    float acc = 0.f;
    for (int k = lane; k < 3200; k += 64)
        acc = fmaf(g[k], fcw[(size_t)n*3200 + k], acc);
    for (int s = 32; s >= 1; s >>= 1) acc += __shfl_down(acc, s, 64);
    if (lane == 0) h[n] = acc + fcb[n];
}

// ---------------- K6b: LIF2 + output LI cell + write voltages[t] ----------------
// grid 1, block 640 (10 waves: one per output class)
__global__ __launch_bounds__(640) void k_head(
        const float* __restrict__ h, float* __restrict__ v2, float* __restrict__ i2,
        float* __restrict__ vo, float* __restrict__ io,
        const float* __restrict__ outw, float* __restrict__ out, int t) {
    __shared__ float spk[500];
    __shared__ float vout[10];
    int tid = threadIdx.x;
    if (tid < 500) {
        float v = v2[tid], cur = i2[tid];
        float vd = v + DTMEM*(cur - v);
        float z = (vd > 1.0f) ? 1.0f : 0.0f;
        v2[tid] = (1.0f - z)*vd;
        i2[tid] = (cur - DTSYN*cur) + h[tid];
        spk[tid] = z;
    }
    __syncthreads();
    int wid = tid >> 6, lane = tid & 63;
    float acc = 0.f;
    for (int n = lane; n < 500; n += 64)
        acc = fmaf(spk[n], outw[wid*500 + n], acc);
    for (int s = 32; s >= 1; s >>= 1) acc += __shfl_down(acc, s, 64);
    if (lane == 0) {
        float ij = io[wid] + acc;
        float vn = vo[wid] + DTMEM*(ij - vo[wid]);
        io[wid] = ij - DTSYN*ij;
        vo[wid] = vn;
        vout[wid] = vn;
    }
    __syncthreads();
    if (tid < 320) out[(size_t)t*320 + tid] = vout[tid % 10];
}

// ---------------- launcher ----------------
extern "C" void kernel_launch(void* const* d_in, const int* in_sizes, int n_in,
                              void* d_out, int out_size, void* d_ws, size_t ws_size,
                              hipStream_t stream) {
    const float* x    = (const float*)d_in[0];
    const float* b1   = (const float*)d_in[1];
    const float* b2   = (const float*)d_in[2];
    const float* w1   = (const float*)d_in[3];
    const float* w2   = (const float*)d_in[4];
    const float* fcw  = (const float*)d_in[5];
    const float* fcb  = (const float*)d_in[6];
    const float* outw = (const float*)d_in[7];
    float* ws  = (float*)d_ws;
    float* out = (float*)d_out;

    // DoG difference kernel, fp32 host math to mirror the fp32 reference
    DK dk;
    {
        float g1[25], g2[25], s1 = 0.f, s2 = 0.f;
        for (int i = 0; i < 5; i++)
            for (int j = 0; j < 5; j++) {
                float ai = (float)(i - 2), aj = (float)(j - 2);
                float r2 = ai*ai + aj*aj;
                g1[i*5+j] = expf(-r2/2.0f);
                g2[i*5+j] = expf(-r2/8.0f);
                s1 += g1[i*5+j]; s2 += g2[i*5+j];
            }
        for (int k = 0; k < 25; k++) dk.v[k] = g1[k]/s1 - g2[k]/s2;
    }

    // weight working copies + zero all state (harness poisons ws with 0xAA)
    hipMemcpyAsync(ws + OW1, w1, 1500*sizeof(float), hipMemcpyDeviceToDevice, stream);
    hipMemcpyAsync(ws + OW2, w2, 75000*sizeof(float), hipMemcpyDeviceToDevice, stream);
    hipMemsetAsync(ws + OV0, 0, (OTOT - OV0)*sizeof(float), stream);

    for (int t = 0; t < T; t++) {
        k_dog<<<(B*LD + 255)/256, 256, 0, stream>>>(x, b1, b2, ws+OZ0, ws+OTP1, dk, t);
        k_conv1lif<<<dim3((L1N + 255)/256, B*30), 256, 0, stream>>>(
            ws+OW1, ws+OZ0, ws+OV0, ws+OI0, ws+OZ2, ws+OTQ1);
        k_stdp1_part<<<dim3(4, 30), 512, 0, stream>>>(
            ws+OTP1, ws+OZ2, ws+OZ0, ws+OTQ1, ws+OP1);
        k_stdp1_apply<<<6, 256, 0, stream>>>(ws+OW1, ws+OP1);
        k_pool<<<(B*30*LP + 255)/256, 256, 0, stream>>>(ws+OZ2, ws+OZ3, ws+OTP2);
        k_conv2lif<<<dim3(25, B), 576, 0, stream>>>(
            ws+OW2, ws+OZ3, ws+OV1, ws+OI1, ws+OZ4, ws+OTQ2, ws+OG);
        k_stdp2_corr<<<dim3(50, 30), 576, 0, stream>>>(ws+OTP2, ws+OZ4, ws+OE2P);
        k_stdp2_corr<<<dim3(50, 30), 576, 0, stream>>>(ws+OZ3, ws+OTQ2, ws+OE2M);
        k_stdp2_apply<<<(75000 + 255)/256, 256, 0, stream>>>(ws+OW2, ws+OE2P, ws+OE2M);
        k_fc1<<<500, 64, 0, stream>>>(ws+OG, fcw, fcb, ws+OH);
        k_head<<<1, 640, 0, stream>>>(ws+OH, ws+OV2, ws+OI2, ws+OVO, ws+OIO, outw, out, t);
    }
}

// Round 2
// 4788.725 us; speedup vs baseline: 5.3002x; 5.3002x over previous
//
#include <hip/hip_runtime.h>
#include <math.h>

// ---------------- constants ----------------
#define DTMEM 0.1f   // DT*TAU_MEM_INV
#define DTSYN 0.2f   // DT*TAU_SYN_INV
#define DTTR  0.02f  // DT*TAU_PRE_INV == DT*TAU_POST_INV

static constexpr int B = 32, T = 32;
static constexpr int HD = 60, H1 = 56, HP = 28, H2 = 24;
static constexpr int LD  = HD*HD;   // 3600
static constexpr int L1N = H1*H1;   // 3136
static constexpr int LP  = HP*HP;   // 784
static constexpr int L2N = H2*H2;   // 576

// float offsets into workspace (all /4-aligned where float4 access happens)
static constexpr size_t OW1  = 0;                           // 1500
static constexpr size_t OW2  = OW1 + 1500;                  // 75000
static constexpr size_t OV0  = OW2 + 75000;                 // zero-init region starts here
static constexpr size_t OI0  = OV0  + (size_t)B*30*L1N;
static constexpr size_t OTQ1 = OI0  + (size_t)B*30*L1N;
static constexpr size_t OZ2  = OTQ1 + (size_t)B*30*L1N;
static constexpr size_t OTP1 = OZ2  + (size_t)B*30*L1N;     // [B,60,60] (channel 0 only)
static constexpr size_t OZ0  = OTP1 + (size_t)B*LD;         // [B,60,60] (channel 0 only)
static constexpr size_t OZ3  = OZ0  + (size_t)B*LD;         // [B,30,28,28]
static constexpr size_t OTP2 = OZ3  + (size_t)B*30*LP;
static constexpr size_t OV1  = OTP2 + (size_t)B*30*LP;      // [B,100,24,24]
static constexpr size_t OI1  = OV1  + (size_t)B*100*L2N;
static constexpr size_t OTQ2 = OI1  + (size_t)B*100*L2N;
static constexpr size_t OZ4  = OTQ2 + (size_t)B*100*L2N;
static constexpr size_t OE2P = OZ4  + (size_t)B*100*L2N;    // [100,30,25]
static constexpr size_t OE2M = OE2P + 75000;
static constexpr size_t OP1  = OE2M + 75000;                // stdp1 partials [30][50][32]
static constexpr size_t OG   = OP1  + 48000;                // [3200]
static constexpr size_t OH   = OG   + 3200;                 // [500]
static constexpr size_t OV2  = OH   + 500;
static constexpr size_t OI2  = OV2  + 500;
static constexpr size_t OVO  = OI2  + 500;
static constexpr size_t OIO  = OVO  + 10;
static constexpr size_t OCNZ = OIO  + 10;                   // int[960] channel-nonzero flags
static constexpr size_t OTOT = OCNZ + 960;                  // ~21.43M floats (~85.7 MB)

struct DK { float v[25]; };

// ---------------- K1: DoG conv (channel 0) + tp1 trace update ----------------
__global__ void k_dog(const float* __restrict__ x, const float* __restrict__ b1,
                      const float* __restrict__ b2, float* __restrict__ z0,
                      float* __restrict__ tp1, DK dk, int t) {
    int idx = blockIdx.x*blockDim.x + threadIdx.x;
    if (idx >= B*LD) return;
    int b = idx / LD, r = idx % LD, y = r / HD, xx = r % HD;
    const float* xp = x + ((size_t)t*B + b)*4096;
    float acc = 0.f;
    #pragma unroll
    for (int kh = 0; kh < 5; kh++)
        #pragma unroll
        for (int kw = 0; kw < 5; kw++)
            acc = fmaf(dk.v[kh*5+kw], xp[(y+kh)*64 + xx + kw], acc);
    float zv = acc + (b1[0] - b2[0]);
    z0[idx] = zv;
    float tp = tp1[idx];
    tp1[idx] = tp + DTTR*(zv - tp);
}

// ---------------- K2: conv1 row-based + LIF0 + tq1 trace ----------------
// grid (8 og, 32 b), block 448 = 4 oo x (56 y x 2 xh). Stage z0 channel once;
// rows read as ds_read_b128, each feeds 5 kw-taps x 28 outputs from registers.
__global__ __launch_bounds__(448) void k_conv1lif(
        const float* __restrict__ w1c, const float* __restrict__ z0,
        float* __restrict__ v0, float* __restrict__ i0,
        float* __restrict__ z2, float* __restrict__ tq1) {
    __shared__ __attribute__((aligned(16))) float zsh[3600];
    __shared__ float wd[100];
    int og = blockIdx.x, b = blockIdx.y, tid = threadIdx.x;
    // stage z0 channel (14.4 KB) via float4
    {
        const float4* src = (const float4*)(z0 + (size_t)b*LD);
        float4* dst = (float4*)zsh;
        for (int i = tid; i < 900; i += 448) dst[i] = src[i];
    }
    if (tid < 100) {
        int oo2 = tid / 25, p = tid % 25, o2 = og*4 + oo2;
        wd[tid] = (o2 < 30) ? (w1c[o2*50 + p] - w1c[o2*50 + 25 + p]) : 0.f;
    }
    int oo = tid & 3, xh = (tid >> 2) & 1, y = tid >> 3;
    int o = og*4 + oo, x0 = xh*28;
    __syncthreads();
    if (o >= 30) return;   // no further syncs
    float acc[28];
    #pragma unroll
    for (int x = 0; x < 28; x++) acc[x] = 0.f;
    #pragma unroll
    for (int kh = 0; kh < 5; kh++) {
        float rr[32];
        const float4* r4 = (const float4*)&zsh[(y+kh)*HD + x0];
        #pragma unroll
        for (int i = 0; i < 8; i++) ((float4*)rr)[i] = r4[i];
        #pragma unroll
        for (int kw = 0; kw < 5; kw++) {
            float w = wd[oo*25 + kh*5 + kw];
            #pragma unroll
            for (int x = 0; x < 28; x++) acc[x] = fmaf(w, rr[x+kw], acc[x]);
        }
    }
    // LIF epilogue on the row segment (float4 x 7)
    size_t n0 = ((size_t)(b*30 + o)*H1 + y)*H1 + x0;
    #pragma unroll
    for (int i = 0; i < 7; i++) {
        float4 v4 = ((const float4*)(v0 + n0))[i];
        float4 c4 = ((const float4*)(i0 + n0))[i];
        float4 t4 = ((const float4*)(tq1 + n0))[i];
        float4 vn, in, zn, tn;
        float* vp = (float*)&v4; float* cp = (float*)&c4; float* tp = (float*)&t4;
        float* vnp = (float*)&vn; float* inp = (float*)&in; float* znp = (float*)&zn; float* tnp = (float*)&tn;
        #pragma unroll
        for (int k = 0; k < 4; k++) {
            float vd = vp[k] + DTMEM*(cp[k] - vp[k]);
            float z = (vd > 15.0f) ? 1.0f : 0.0f;
            vnp[k] = (1.0f - z)*vd;
            inp[k] = (cp[k] - DTSYN*cp[k]) + acc[i*4+k];
            znp[k] = z;
            tnp[k] = tp[k] + DTTR*(z - tp[k]);
        }
        ((float4*)(v0 + n0))[i] = vn;
        ((float4*)(i0 + n0))[i] = in;
        ((float4*)(z2 + n0))[i] = zn;
        ((float4*)(tq1 + n0))[i] = tn;
    }
}

// ---------------- K3: stdp1 correlations, row-based, deterministic reduce ----------------
// grid (8 og, 32 b), block 448. Per thread: z2/tq1 row segment (28) + 5 rows of
// z0/tp1 (32 floats each, b128). Sparsity: skip accp if no z2 spike in segment,
// skip accm if tq1 segment all zero (exact). Butterfly + LDS + partials[o][50][32].
__global__ __launch_bounds__(448) void k_stdp1_part(
        const float* __restrict__ tp1, const float* __restrict__ z2,
        const float* __restrict__ z0, const float* __restrict__ tq1,
        float* __restrict__ part) {
    __shared__ __attribute__((aligned(16))) float z0sh[3600];
    __shared__ __attribute__((aligned(16))) float tp1sh[3600];
    __shared__ float red[7*200];
    int og = blockIdx.x, b = blockIdx.y, tid = threadIdx.x;
    {
        const float4* s0 = (const float4*)(z0 + (size_t)b*LD);
        const float4* s1 = (const float4*)(tp1 + (size_t)b*LD);
        float4* d0 = (float4*)z0sh; float4* d1 = (float4*)tp1sh;
        for (int i = tid; i < 900; i += 448) { d0[i] = s0[i]; d1[i] = s1[i]; }
    }
    int oo = tid & 3, xh = (tid >> 2) & 1, y = tid >> 3;
    int o = og*4 + oo, x0 = xh*28;
    float accp[25], accm[25];
    #pragma unroll
    for (int p = 0; p < 25; p++) { accp[p] = 0.f; accm[p] = 0.f; }
    __syncthreads();
    if (o < 30) {
        int ol = o;  // in-range by guard
        size_t base = ((size_t)(b*30 + ol)*H1 + y)*H1 + x0;
        float zseg[28], qseg[28];
        #pragma unroll
        for (int i = 0; i < 7; i++) {
            ((float4*)zseg)[i] = ((const float4*)(z2 + base))[i];
            ((float4*)qseg)[i] = ((const float4*)(tq1 + base))[i];
        }
        float zs = 0.f, qs = 0.f;
        #pragma unroll
        for (int x = 0; x < 28; x++) { zs += zseg[x]; qs += qseg[x]; }
        if (qs != 0.f) {   // accm: unfold(z0) x tq1
            #pragma unroll
            for (int kh = 0; kh < 5; kh++) {
                float rr[32];
                const float4* r4 = (const float4*)&z0sh[(y+kh)*HD + x0];
                #pragma unroll
                for (int i = 0; i < 8; i++) ((float4*)rr)[i] = r4[i];
                #pragma unroll
                for (int kw = 0; kw < 5; kw++)
                    #pragma unroll
                    for (int x = 0; x < 28; x++)
                        accm[kh*5+kw] = fmaf(rr[x+kw], qseg[x], accm[kh*5+kw]);
            }
        }
        if (zs != 0.f) {   // accp: unfold(tp1) x z2
            #pragma unroll
            for (int kh = 0; kh < 5; kh++) {
                float rr[32];
                const float4* r4 = (const float4*)&tp1sh[(y+kh)*HD + x0];
                #pragma unroll
                for (int i = 0; i < 8; i++) ((float4*)rr)[i] = r4[i];
                #pragma unroll
                for (int kw = 0; kw < 5; kw++)
                    #pragma unroll
                    for (int x = 0; x < 28; x++)
                        accp[kh*5+kw] = fmaf(rr[x+kw], zseg[x], accp[kh*5+kw]);
            }
        }
    }
    // butterfly over xh (mask 4) + y-low bits (8,16,32); lanes 0..3 hold per-oo sums
    int lane = tid & 63, wave = tid >> 6;
    #pragma unroll
    for (int q = 0; q < 50; q++) {
        float v = (q < 25) ? accp[q] : accm[q-25];
        v += __shfl_xor(v, 4, 64);
        v += __shfl_xor(v, 8, 64);
        v += __shfl_xor(v, 16, 64);
        v += __shfl_xor(v, 32, 64);
        if (lane < 4) red[wave*200 + lane*50 + q] = v;
    }
    __syncthreads();
    if (tid < 200) {
        int oo2 = tid / 50, q = tid % 50;
        float s = 0.f;
        #pragma unroll
        for (int w = 0; w < 7; w++) s += red[w*200 + oo2*50 + q];
        int o2 = og*4 + oo2;
        if (o2 < 30) part[((size_t)(o2*50 + q) << 5) + b] = s;
    }
}

// ---------------- K4: stdp1 apply (reduce 32 b-partials, sign trick for on/off) ----------------
__global__ void k_stdp1_apply(float* __restrict__ w1c, const float* __restrict__ part) {
    int e = blockIdx.x*blockDim.x + threadIdx.x;
    if (e >= 1500) return;                  // e = o*50 + c*25 + p == flat w1 index
    int o = e / 50, r = e % 50, c = r / 25, p = r % 25;
    float Ep = 0.f, Em = 0.f;
    #pragma unroll
    for (int s = 0; s < 32; s++) {
        Ep += part[((size_t)(o*50 + p) << 5) + s];
        Em += part[((size_t)(o*50 + 25 + p) << 5) + s];
    }
    float sign = (c == 0) ? 1.0f : -1.0f;
    float w = w1c[e];
    float dwp = 0.004f * fmaxf(1.0f - w, 0.0f) * (sign * Ep);
    float dwm = 0.003f * fmaxf(w, 0.0f) * (sign * Em);
    float wn = w + dwp - dwm;
    w1c[e] = fminf(fmaxf(wn, 0.0f), 1.0f);
}

// ---------------- K5: 2x2 maxpool + tp2 trace + channel-nonzero flags ----------------
// grid 960 (= b*30+c), block 256
__global__ void k_pool(const float* __restrict__ z2, float* __restrict__ z3,
                       float* __restrict__ tp2, int* __restrict__ cnz) {
    __shared__ int s_any;
    int bc = blockIdx.x, tid = threadIdx.x;
    if (tid == 0) s_any = 0;
    __syncthreads();
    bool my = false;
    for (int idx = tid; idx < LP; idx += 256) {
        int y = idx / HP, xx = idx % HP;
        const float* zp = z2 + (size_t)bc*L1N + (2*y)*H1 + 2*xx;
        float m = fmaxf(fmaxf(zp[0], zp[1]), fmaxf(zp[H1], zp[H1+1]));
        size_t n = (size_t)bc*LP + idx;
        z3[n] = m;
        float tp = tp2[n];
        tp2[n] = tp + DTTR*(m - tp);
        my = my || (m != 0.f);
    }
    if (my) atomicOr(&s_any, 1);
    __syncthreads();
    if (tid == 0) cnz[bc] = s_any;
}

// ---------------- K6: conv2 row-based (jb=2) + LIF1 + tq2 + spike flags g ----------------
// grid (13 jg, 32 b), block 192 = 4 jp x 2 xh x 24 y. w staged padded-28 for b128
// reads; pre channel staged per c (skipped entirely when cnz==0, uniform).
__global__ __launch_bounds__(192) void k_conv2lif(
        const float* __restrict__ w2c, const float* __restrict__ z3,
        const int* __restrict__ cnz,
        float* __restrict__ v1, float* __restrict__ i1,
        float* __restrict__ z4, float* __restrict__ tq2, float* __restrict__ g) {
    __shared__ __attribute__((aligned(16))) float wlds[8*30*28];  // [jloc][c][28]
    __shared__ __attribute__((aligned(16))) float spre[LP];
    __shared__ int sjany[8];
    int jg = blockIdx.x, b = blockIdx.y, tid = threadIdx.x;
    int jb0 = jg*8;
    for (int idx = tid; idx < 6720; idx += 192) {
        int j = idx / 840, r = idx % 840, c = r / 28, p = r % 28;
        int jgl = jb0 + j;
        wlds[idx] = (p < 25 && jgl < 100) ? w2c[((size_t)jgl*30 + c)*25 + p] : 0.f;
    }
    if (tid < 8) sjany[tid] = 0;
    int jp = tid & 3, xh = (tid >> 2) & 1, y = tid >> 3;
    int j0 = jb0 + jp*2, x0 = xh*12;
    float acc0[12], acc1[12];
    #pragma unroll
    for (int x = 0; x < 12; x++) { acc0[x] = 0.f; acc1[x] = 0.f; }
    __syncthreads();
    #pragma unroll 1
    for (int c = 0; c < 30; c++) {
        bool act = cnz[b*30 + c] != 0;   // block-uniform
        __syncthreads();
        if (act) {
            const float4* src = (const float4*)(z3 + (size_t)(b*30 + c)*LP);
            float4* dst = (float4*)spre;
            for (int i = tid; i < 196; i += 192) dst[i] = src[i];
        }
        __syncthreads();
        if (!act) continue;
        float wa[28], wb[28];
        #pragma unroll
        for (int i = 0; i < 7; i++) {
            ((float4*)wa)[i] = ((const float4*)&wlds[(jp*2)*840 + c*28])[i];
            ((float4*)wb)[i] = ((const float4*)&wlds[(jp*2+1)*840 + c*28])[i];
        }
        #pragma unroll
        for (int kh = 0; kh < 5; kh++) {
            float rr[16];
            const float4* r4 = (const float4*)&spre[(y+kh)*HP + x0];
            #pragma unroll
            for (int i = 0; i < 4; i++) ((float4*)rr)[i] = r4[i];
            #pragma unroll
            for (int kw = 0; kw < 5; kw++) {
                float w0 = wa[kh*5+kw], w1 = wb[kh*5+kw];
                #pragma unroll
                for (int x = 0; x < 12; x++) {
                    acc0[x] = fmaf(w0, rr[x+kw], acc0[x]);
                    acc1[x] = fmaf(w1, rr[x+kw], acc1[x]);
                }
            }
        }
    }
    // LIF epilogue per j (guard j<100)
    bool spk0 = false, spk1 = false;
    #pragma unroll
    for (int jj = 0; jj < 2; jj++) {
        int j = j0 + jj;
        if (j < 100) {
            size_t n0 = ((size_t)(b*100 + j)*H2 + y)*H2 + x0;
            bool anyspk = false;
            #pragma unroll
            for (int i = 0; i < 3; i++) {
                float4 v4 = ((const float4*)(v1 + n0))[i];
                float4 c4 = ((const float4*)(i1 + n0))[i];
                float4 t4 = ((const float4*)(tq2 + n0))[i];
                float4 vn, in, zn, tn;
                float* vp=(float*)&v4; float* cp=(float*)&c4; float* tp=(float*)&t4;
                float* vnp=(float*)&vn; float* inp=(float*)&in; float* znp=(float*)&zn; float* tnp=(float*)&tn;
                #pragma unroll
                for (int k = 0; k < 4; k++) {
                    float a = jj ? acc1[i*4+k] : acc0[i*4+k];
                    float vd = vp[k] + DTMEM*(cp[k] - vp[k]);
                    float z = (vd > 10.0f) ? 1.0f : 0.0f;
                    vnp[k] = (1.0f - z)*vd;
                    inp[k] = (cp[k] - DTSYN*cp[k]) + 10.0f*a;
                    znp[k] = z;
                    tnp[k] = tp[k] + DTTR*(z - tp[k]);
                    anyspk = anyspk || (z != 0.f);
                }
                ((float4*)(v1 + n0))[i] = vn;
                ((float4*)(i1 + n0))[i] = in;
                ((float4*)(z4 + n0))[i] = zn;
                ((float4*)(tq2 + n0))[i] = tn;
            }
            if (jj == 0) spk0 = anyspk; else spk1 = anyspk;
        }
    }
    if (spk0) atomicOr(&sjany[jp*2], 1);
    if (spk1) atomicOr(&sjany[jp*2+1], 1);
    __syncthreads();
    if (tid < 8 && jb0 + tid < 100) g[b*100 + jb0 + tid] = sjany[tid] ? 1.f : 0.f;
}

// ---------------- K7: stdp2 correlation, row-based, jb=2, deterministic ----------------
// E[j,c,p] = sum_{b,y,x} pre[b,c,y+kh,x+kw] * post[b,j,y,x]
// MODE 0 (E+): pre=tp2, post=z4; skip per-b via g spike flags.
// MODE 1 (E-): pre=z3,  post=tq2; skip per-b via cnz (uniform).
// grid (13 jg, 30 c), block 192 = 4 jp x 2 xh x 24 y.
template<int MODE>
__global__ __launch_bounds__(192) void k_corr(
        const float* __restrict__ pre, const float* __restrict__ post,
        float* __restrict__ E, const float* __restrict__ gflag,
        const int* __restrict__ cnz) {
    __shared__ __attribute__((aligned(16))) float spre[LP];
    __shared__ float sflag[8];
    __shared__ float red[3*200];
    int jg = blockIdx.x, c = blockIdx.y, tid = threadIdx.x;
    int jb0 = jg*8;
    int jp = tid & 3, xh = (tid >> 2) & 1, y = tid >> 3;
    int j0 = jb0 + jp*2, x0 = xh*12;
    int jl0 = (j0 < 100) ? j0 : 99;        // clamp for safe loads; results discarded
    int jl1 = (j0+1 < 100) ? j0+1 : 99;
    float accA[25], accB[25];
    #pragma unroll
    for (int p = 0; p < 25; p++) { accA[p] = 0.f; accB[p] = 0.f; }
    #pragma unroll 1
    for (int b = 0; b < B; b++) {
        __syncthreads();   // protect spre/sflag from previous iteration readers
        if (MODE == 0 && tid < 8)
            sflag[tid] = (jb0 + tid < 100) ? gflag[b*100 + jb0 + tid] : 0.f;
        __syncthreads();
        bool anyb;
        if (MODE == 0)
            anyb = (sflag[0] + sflag[1] + sflag[2] + sflag[3] +
                    sflag[4] + sflag[5] + sflag[6] + sflag[7]) != 0.f;
        else
            anyb = cnz[b*30 + c] != 0;
        if (anyb) {
            const float4* src = (const float4*)(pre + (size_t)(b*30 + c)*LP);
            float4* dst = (float4*)spre;
            for (int i = tid; i < 196; i += 192) dst[i] = src[i];
        }
        __syncthreads();
        if (!anyb) continue;
        bool mine = true;
        if (MODE == 0) mine = (sflag[jp*2] != 0.f) || (sflag[jp*2+1] != 0.f);
        if (!mine) continue;
        float pA[12], pB[12];
        {
            size_t nA = ((size_t)(b*100 + jl0)*H2 + y)*H2 + x0;
            size_t nB = ((size_t)(b*100 + jl1)*H2 + y)*H2 + x0;
            #pragma unroll
            for (int i = 0; i < 3; i++) {
                ((float4*)pA)[i] = ((const float4*)(post + nA))[i];
                ((float4*)pB)[i] = ((const float4*)(post + nB))[i];
            }
        }
        #pragma unroll
        for (int kh = 0; kh < 5; kh++) {
            float rr[16];
            const float4* r4 = (const float4*)&spre[(y+kh)*HP + x0];
            #pragma unroll
            for (int i = 0; i < 4; i++) ((float4*)rr)[i] = r4[i];
            #pragma unroll
            for (int kw = 0; kw < 5; kw++)
                #pragma unroll
                for (int x = 0; x < 12; x++) {
                    accA[kh*5+kw] = fmaf(rr[x+kw], pA[x], accA[kh*5+kw]);
                    accB[kh*5+kw] = fmaf(rr[x+kw], pB[x], accB[kh*5+kw]);
                }
        }
    }
    int lane = tid & 63, wave = tid >> 6;
    #pragma unroll
    for (int q = 0; q < 50; q++) {
        float v = (q < 25) ? accA[q] : accB[q-25];
        v += __shfl_xor(v, 4, 64);
        v += __shfl_xor(v, 8, 64);
        v += __shfl_xor(v, 16, 64);
        v += __shfl_xor(v, 32, 64);
        if (lane < 4) red[wave*200 + lane*50 + q] = v;
    }
    __syncthreads();
    if (tid < 200) {
        int jp2 = tid / 50, q = tid % 50;
        float s = red[0*200 + jp2*50 + q] + red[1*200 + jp2*50 + q] + red[2*200 + jp2*50 + q];
        int j = jb0 + jp2*2 + ((q < 25) ? 0 : 1), p = q % 25;
        if (j < 100) E[((size_t)j*30 + c)*25 + p] = s;
    }
}

// ---------------- K8: stdp2 apply ----------------
__global__ void k_stdp2_apply(float* __restrict__ w2c, const float* __restrict__ Ep,
                              const float* __restrict__ Em) {
    int e = blockIdx.x*blockDim.x + threadIdx.x;
    if (e >= 75000) return;        // flat [j][c][p] matches both w2 and E layouts
    float w = w2c[e];
    float dwp = 0.004f * fmaxf(1.0f - w, 0.0f) * Ep[e];
    float dwm = 0.003f * fmaxf(w, 0.0f) * Em[e];
    float wn = w + dwp - dwm;
    w2c[e] = fminf(fmaxf(wn, 0.0f), 1.0f);
}

// ---------------- K9: fc1 (500x3200), float4, one wave per row ----------------
__global__ __launch_bounds__(256) void k_fc1(const float* __restrict__ g,
                                             const float* __restrict__ fcw,
                                             const float* __restrict__ fcb,
                                             float* __restrict__ h) {
    int w = threadIdx.x >> 6, lane = threadIdx.x & 63;
    int n = blockIdx.x*4 + w;    // 125*4 = 500 exactly
    const float4* g4 = (const float4*)g;
    const float4* w4 = (const float4*)(fcw + (size_t)n*3200);
    float acc = 0.f;
    for (int k = lane; k < 800; k += 64) {
        float4 gv = g4[k], wv = w4[k];
        acc = fmaf(gv.x, wv.x, acc);
        acc = fmaf(gv.y, wv.y, acc);
        acc = fmaf(gv.z, wv.z, acc);
        acc = fmaf(gv.w, wv.w, acc);
    }
    #pragma unroll
    for (int s = 32; s >= 1; s >>= 1) acc += __shfl_down(acc, s, 64);
    if (lane == 0) h[n] = acc + fcb[n];
}

// ---------------- K10: LIF2 + output LI cell + write voltages[t] ----------------
__global__ __launch_bounds__(640) void k_head(
        const float* __restrict__ h, float* __restrict__ v2, float* __restrict__ i2,
        float* __restrict__ vo, float* __restrict__ io,
        const float* __restrict__ outw, float* __restrict__ out, int t) {
    __shared__ float spk[500];
    __shared__ float vout[10];
    int tid = threadIdx.x;
    if (tid < 500) {
        float v = v2[tid], cur = i2[tid];
        float vd = v + DTMEM*(cur - v);
        float z = (vd > 1.0f) ? 1.0f : 0.0f;
        v2[tid] = (1.0f - z)*vd;
        i2[tid] = (cur - DTSYN*cur) + h[tid];
        spk[tid] = z;
    }
    __syncthreads();
    int wid = tid >> 6, lane = tid & 63;
    float acc = 0.f;
    for (int n = lane; n < 500; n += 64)
        acc = fmaf(spk[n], outw[wid*500 + n], acc);
    #pragma unroll
    for (int s = 32; s >= 1; s >>= 1) acc += __shfl_down(acc, s, 64);
    if (lane == 0) {
        float ij = io[wid] + acc;
        float vn = vo[wid] + DTMEM*(ij - vo[wid]);
        io[wid] = ij - DTSYN*ij;
        vo[wid] = vn;
        vout[wid] = vn;
    }
    __syncthreads();
    if (tid < 320) out[(size_t)t*320 + tid] = vout[tid % 10];
}

// ---------------- launcher ----------------
extern "C" void kernel_launch(void* const* d_in, const int* in_sizes, int n_in,
                              void* d_out, int out_size, void* d_ws, size_t ws_size,
                              hipStream_t stream) {
    const float* x    = (const float*)d_in[0];
    const float* b1   = (const float*)d_in[1];
    const float* b2   = (const float*)d_in[2];
    const float* w1   = (const float*)d_in[3];
    const float* w2   = (const float*)d_in[4];
    const float* fcw  = (const float*)d_in[5];
    const float* fcb  = (const float*)d_in[6];
    const float* outw = (const float*)d_in[7];
    float* ws  = (float*)d_ws;
    float* out = (float*)d_out;

    DK dk;
    {
        float g1[25], g2[25], s1 = 0.f, s2 = 0.f;
        for (int i = 0; i < 5; i++)
            for (int j = 0; j < 5; j++) {
                float ai = (float)(i - 2), aj = (float)(j - 2);
                float r2 = ai*ai + aj*aj;
                g1[i*5+j] = expf(-r2/2.0f);
                g2[i*5+j] = expf(-r2/8.0f);
                s1 += g1[i*5+j]; s2 += g2[i*5+j];
            }
        for (int k = 0; k < 25; k++) dk.v[k] = g1[k]/s1 - g2[k]/s2;
    }

    hipMemcpyAsync(ws + OW1, w1, 1500*sizeof(float), hipMemcpyDeviceToDevice, stream);
    hipMemcpyAsync(ws + OW2, w2, 75000*sizeof(float), hipMemcpyDeviceToDevice, stream);
    hipMemsetAsync(ws + OV0, 0, (OTOT - OV0)*sizeof(float), stream);

    for (int t = 0; t < T; t++) {
        k_dog<<<(B*LD + 255)/256, 256, 0, stream>>>(x, b1, b2, ws+OZ0, ws+OTP1, dk, t);
        k_conv1lif<<<dim3(8, 32), 448, 0, stream>>>(
            ws+OW1, ws+OZ0, ws+OV0, ws+OI0, ws+OZ2, ws+OTQ1);
        k_stdp1_part<<<dim3(8, 32), 448, 0, stream>>>(
            ws+OTP1, ws+OZ2, ws+OZ0, ws+OTQ1, ws+OP1);
        k_stdp1_apply<<<6, 256, 0, stream>>>(ws+OW1, ws+OP1);
        k_pool<<<960, 256, 0, stream>>>(ws+OZ2, ws+OZ3, ws+OTP2, (int*)(ws+OCNZ));
        k_conv2lif<<<dim3(13, 32), 192, 0, stream>>>(
            ws+OW2, ws+OZ3, (int*)(ws+OCNZ), ws+OV1, ws+OI1, ws+OZ4, ws+OTQ2, ws+OG);
        k_corr<0><<<dim3(13, 30), 192, 0, stream>>>(
            ws+OTP2, ws+OZ4, ws+OE2P, ws+OG, nullptr);
        k_corr<1><<<dim3(13, 30), 192, 0, stream>>>(
            ws+OZ3, ws+OTQ2, ws+OE2M, nullptr, (int*)(ws+OCNZ));
        k_stdp2_apply<<<294, 256, 0, stream>>>(ws+OW2, ws+OE2P, ws+OE2M);
        k_fc1<<<125, 256, 0, stream>>>(ws+OG, fcw, fcb, ws+OH);
        k_head<<<1, 640, 0, stream>>>(ws+OH, ws+OV2, ws+OI2, ws+OVO, ws+OIO, outw, out, t);
    }
}

// Round 3
// 3394.748 us; speedup vs baseline: 7.4766x; 1.4106x over previous
//
#include <hip/hip_runtime.h>
#include <math.h>

// ---------------- constants ----------------
#define DTMEM 0.1f   // DT*TAU_MEM_INV
#define DTSYN 0.2f   // DT*TAU_SYN_INV
#define DTTR  0.02f  // DT*TAU_PRE_INV == DT*TAU_POST_INV

static constexpr int B = 32, T = 32;
static constexpr int HD = 60, H1 = 56, HP = 28, H2 = 24;
static constexpr int LD  = HD*HD;   // 3600
static constexpr int L1N = H1*H1;   // 3136
static constexpr int LP  = HP*HP;   // 784
static constexpr int L2N = H2*H2;   // 576

// float offsets into workspace (all multiples of 4 for float4 access)
static constexpr size_t OW1   = 0;                            // 1500
static constexpr size_t OW2   = OW1 + 1500;                   // 75000
static constexpr size_t OV0   = OW2 + 75000;                  // 76500 (div by 4) zero-region start
static constexpr size_t OI0   = OV0   + (size_t)B*30*L1N;
static constexpr size_t OTQ1  = OI0   + (size_t)B*30*L1N;
static constexpr size_t OTP1A = OTQ1  + (size_t)B*30*L1N;     // [B,60,60] ping
static constexpr size_t OTP1B = OTP1A + (size_t)B*LD;         // [B,60,60] pong
static constexpr size_t OZ3   = OTP1B + (size_t)B*LD;         // [B,30,28,28]
static constexpr size_t OTP2  = OZ3   + (size_t)B*30*LP;
static constexpr size_t OV1   = OTP2  + (size_t)B*30*LP;      // [B,100,24,24]
static constexpr size_t OI1   = OV1   + (size_t)B*100*L2N;
static constexpr size_t OTQ2  = OI1   + (size_t)B*100*L2N;
static constexpr size_t OZ4   = OTQ2  + (size_t)B*100*L2N;
static constexpr size_t OE2P  = OZ4   + (size_t)B*100*L2N;    // [100,30,25]
static constexpr size_t OE2M  = OE2P  + 75000;
static constexpr size_t OP1   = OE2M  + 75000;                // stdp1 partials [30][50][32]
static constexpr size_t OG    = OP1   + 48000;                // [T][3200] per-step spike flags
static constexpr size_t OHH   = OG    + (size_t)T*3200;       // [T][500]
static constexpr size_t OW2P  = OHH   + (size_t)T*500;        // padded w2 [100][30][28]
static constexpr size_t OCNZ  = OW2P  + 84000;                // int[960][2]
static constexpr size_t OTOT  = OCNZ  + 1920;                 // ~18.5M floats (~74 MB)

struct DK { float v[25]; };

// ================= K_front: DoG + tp1 + conv1 + LIF0 + tq1 + stdp1-partials
//                   + maxpool + tp2 + cnz flags =================
// grid (8 og, 32 b), block 448 = (oo:4, xh:2, y:56). tid = y*8 + xh*4 + oo.
__global__ __launch_bounds__(448) void k_front(
        const float* __restrict__ x, const float* __restrict__ b1,
        const float* __restrict__ b2, const float* __restrict__ w1c,
        const float* __restrict__ tp1r, float* __restrict__ tp1w,
        float* __restrict__ v0, float* __restrict__ i0, float* __restrict__ tq1,
        float* __restrict__ z3, float* __restrict__ tp2,
        float* __restrict__ part, int* __restrict__ cnz2, DK dk, int t) {
    __shared__ __attribute__((aligned(16))) float xsh[4096];
    __shared__ __attribute__((aligned(16))) float zsh[3600];   // DoG out (= z ch0)
    __shared__ __attribute__((aligned(16))) float tsh[3600];   // tp1 (updated)
    __shared__ float wd[100];
    __shared__ float red[7*200];
    __shared__ int sflags[8];
    int og = blockIdx.x, b = blockIdx.y, tid = threadIdx.x;
    // stage x frame + tp1_old
    {
        const float4* xs = (const float4*)(x + ((size_t)t*B + b)*4096);
        const float4* ts = (const float4*)(tp1r + (size_t)b*LD);
        float4* xd = (float4*)xsh; float4* td = (float4*)tsh;
        for (int i = tid; i < 1024; i += 448) xd[i] = xs[i];
        for (int i = tid; i < 900; i += 448) td[i] = ts[i];
    }
    if (tid < 100) {
        int oo2 = tid / 25, p = tid % 25;
        int o2 = og*4 + oo2; if (o2 > 29) o2 = 29;   // clamp: values unused for o2>=30
        wd[tid] = w1c[o2*50 + p] - w1c[o2*50 + 25 + p];
    }
    if (tid < 8) sflags[tid] = 0;
    __syncthreads();
    float bias = b1[0] - b2[0];
    // DoG + tp1 trace update (in LDS; og==0 persists tp1 to pong buffer)
    for (int idx = tid; idx < 3600; idx += 448) {
        int yy = idx / 60, xx2 = idx % 60;
        float a = 0.f;
        #pragma unroll
        for (int kh = 0; kh < 5; kh++)
            #pragma unroll
            for (int kw = 0; kw < 5; kw++)
                a = fmaf(dk.v[kh*5+kw], xsh[(yy+kh)*64 + xx2 + kw], a);
        float zv = a + bias;
        zsh[idx] = zv;
        float tp = tsh[idx];
        tp = tp + DTTR*(zv - tp);
        tsh[idx] = tp;
        if (og == 0) tp1w[(size_t)b*LD + idx] = tp;
    }
    __syncthreads();
    int oo = tid & 3, xh = (tid >> 2) & 1, y = tid >> 3;
    int o = og*4 + oo, x0 = xh*28;
    bool valid = (o < 30);
    float accp[25], accm[25];
    #pragma unroll
    for (int p = 0; p < 25; p++) { accp[p] = 0.f; accm[p] = 0.f; }
    bool anym = false;
    if (valid) {
        // conv1 (collapsed on/off channel)
        float acc[28];
        #pragma unroll
        for (int xq = 0; xq < 28; xq++) acc[xq] = 0.f;
        #pragma unroll
        for (int kh = 0; kh < 5; kh++) {
            float rr[32];
            const float4* r4 = (const float4*)&zsh[(y+kh)*HD + x0];
            #pragma unroll
            for (int i = 0; i < 8; i++) ((float4*)rr)[i] = r4[i];
            #pragma unroll
            for (int kw = 0; kw < 5; kw++) {
                float w = wd[oo*25 + kh*5 + kw];
                #pragma unroll
                for (int xq = 0; xq < 28; xq++) acc[xq] = fmaf(w, rr[xq+kw], acc[xq]);
            }
        }
        // LIF0 + tq1 epilogue; keep spikes zn + trace tn in regs
        float zn[28], tn[28];
        size_t n0 = ((size_t)(b*30 + o)*H1 + y)*H1 + x0;
        #pragma unroll
        for (int i = 0; i < 7; i++) {
            float4 v4 = ((const float4*)(v0 + n0))[i];
            float4 c4 = ((const float4*)(i0 + n0))[i];
            float4 t4 = ((const float4*)(tq1 + n0))[i];
            float4 vn, in, tn4;
            float* vp=(float*)&v4; float* cp=(float*)&c4; float* tp=(float*)&t4;
            float* vnp=(float*)&vn; float* inp=(float*)&in; float* tnp=(float*)&tn4;
            #pragma unroll
            for (int k = 0; k < 4; k++) {
                float vd = vp[k] + DTMEM*(cp[k] - vp[k]);
                float z = (vd > 15.0f) ? 1.0f : 0.0f;
                vnp[k] = (1.0f - z)*vd;
                inp[k] = (cp[k] - DTSYN*cp[k]) + acc[i*4+k];
                float tq = tp[k] + DTTR*(z - tp[k]);
                tnp[k] = tq;
                zn[i*4+k] = z; tn[i*4+k] = tq;
            }
            ((float4*)(v0 + n0))[i] = vn;
            ((float4*)(i0 + n0))[i] = in;
            ((float4*)(tq1 + n0))[i] = tn4;
        }
        // stdp1 partial correlations (sparsity-gated, exact)
        float zs = 0.f, qs = 0.f;
        #pragma unroll
        for (int xq = 0; xq < 28; xq++) { zs += zn[xq]; qs += tn[xq]; }
        if (qs != 0.f) {   // accm: unfold(z0) x tq1_new
            #pragma unroll
            for (int kh = 0; kh < 5; kh++) {
                float rr[32];
                const float4* r4 = (const float4*)&zsh[(y+kh)*HD + x0];
                #pragma unroll
                for (int i = 0; i < 8; i++) ((float4*)rr)[i] = r4[i];
                #pragma unroll
                for (int kw = 0; kw < 5; kw++)
                    #pragma unroll
                    for (int xq = 0; xq < 28; xq++)
                        accm[kh*5+kw] = fmaf(rr[xq+kw], tn[xq], accm[kh*5+kw]);
            }
        }
        if (zs != 0.f) {   // accp: unfold(tp1_new) x z2
            #pragma unroll
            for (int kh = 0; kh < 5; kh++) {
                float rr[32];
                const float4* r4 = (const float4*)&tsh[(y+kh)*HD + x0];
                #pragma unroll
                for (int i = 0; i < 8; i++) ((float4*)rr)[i] = r4[i];
                #pragma unroll
                for (int kw = 0; kw < 5; kw++)
                    #pragma unroll
                    for (int xq = 0; xq < 28; xq++)
                        accp[kh*5+kw] = fmaf(rr[xq+kw], zn[xq], accp[kh*5+kw]);
            }
        }
        // 2x2 maxpool via shuffle with y-partner (tid^8), + tp2 trace
        float mx[14];
        #pragma unroll
        for (int k = 0; k < 14; k++) mx[k] = fmaxf(zn[2*k], zn[2*k+1]);
        #pragma unroll
        for (int k = 0; k < 14; k++) {
            float pm = __shfl_xor(mx[k], 8, 64);
            mx[k] = fmaxf(mx[k], pm);
        }
        if ((y & 1) == 0) {
            int py = y >> 1;
            size_t pb = ((size_t)(b*30 + o)*HP + py)*HP + xh*14;
            #pragma unroll
            for (int k = 0; k < 14; k++) {
                float m = mx[k];
                anym = anym || (m != 0.f);
                z3[pb + k] = m;
                float tpv = tp2[pb + k];
                tp2[pb + k] = tpv + DTTR*(m - tpv);
            }
        }
    }
    if (anym) atomicOr(&sflags[oo*2 + xh], 1);
    // deterministic partial reduction (butterfly over xh + 3 y bits, then LDS)
    int lane = tid & 63, wave = tid >> 6;
    #pragma unroll
    for (int q = 0; q < 50; q++) {
        float v = (q < 25) ? accp[q] : accm[q-25];
        v += __shfl_xor(v, 4, 64);
        v += __shfl_xor(v, 8, 64);
        v += __shfl_xor(v, 16, 64);
        v += __shfl_xor(v, 32, 64);
        if (lane < 4) red[wave*200 + lane*50 + q] = v;
    }
    __syncthreads();
    if (tid < 200) {
        int oo2 = tid / 50, q = tid % 50;
        float s = 0.f;
        #pragma unroll
        for (int w = 0; w < 7; w++) s += red[w*200 + oo2*50 + q];
        int o2 = og*4 + oo2;
        if (o2 < 30) part[((size_t)(o2*50 + q) << 5) + b] = s;
    }
    if (tid < 8) {
        int o2 = og*4 + (tid >> 1);
        if (o2 < 30) cnz2[(b*30 + o2)*2 + (tid & 1)] = sflags[tid];
    }
}

// ================= K_B: conv2 (jb=2, weights from padded global) + LIF1 + tq2 + g =================
// grid (13 jg, 32 b), block 192 = (jp:4, xh:2, y:24)
__global__ __launch_bounds__(192) void k_conv2lif(
        const float* __restrict__ w2p, const float* __restrict__ z3,
        const int* __restrict__ cnz2,
        float* __restrict__ v1, float* __restrict__ i1,
        float* __restrict__ z4, float* __restrict__ tq2, float* __restrict__ g_t) {
    __shared__ __attribute__((aligned(16))) float spre[LP];
    __shared__ int sjany[8];
    int jg = blockIdx.x, b = blockIdx.y, tid = threadIdx.x;
    int jb0 = jg*8;
    if (tid < 8) sjany[tid] = 0;
    int jp = tid & 3, xh = (tid >> 2) & 1, y = tid >> 3;
    int j0 = jb0 + jp*2, x0 = xh*12;
    int ja = (j0 < 100) ? j0 : 99;        // clamped addr for loads; stores guarded
    int jbb = (j0+1 < 100) ? j0+1 : 99;
    float acc0[12], acc1[12];
    #pragma unroll
    for (int xq = 0; xq < 12; xq++) { acc0[xq] = 0.f; acc1[xq] = 0.f; }
    #pragma unroll 1
    for (int c = 0; c < 30; c++) {
        bool act = (cnz2[(b*30 + c)*2] | cnz2[(b*30 + c)*2 + 1]) != 0;
        __syncthreads();
        if (act) {
            const float4* src = (const float4*)(z3 + (size_t)(b*30 + c)*LP);
            float4* dst = (float4*)spre;
            for (int i = tid; i < 196; i += 192) dst[i] = src[i];
        }
        __syncthreads();
        if (!act) continue;
        float wa[28], wb[28];
        #pragma unroll
        for (int i = 0; i < 7; i++) {
            ((float4*)wa)[i] = ((const float4*)(w2p + ((size_t)ja*30 + c)*28))[i];
            ((float4*)wb)[i] = ((const float4*)(w2p + ((size_t)jbb*30 + c)*28))[i];
        }
        #pragma unroll
        for (int kh = 0; kh < 5; kh++) {
            float rr[16];
            const float4* r4 = (const float4*)&spre[(y+kh)*HP + x0];
            #pragma unroll
            for (int i = 0; i < 4; i++) ((float4*)rr)[i] = r4[i];
            #pragma unroll
            for (int kw = 0; kw < 5; kw++) {
                float w0 = wa[kh*5+kw], w1 = wb[kh*5+kw];
                #pragma unroll
                for (int xq = 0; xq < 12; xq++) {
                    acc0[xq] = fmaf(w0, rr[xq+kw], acc0[xq]);
                    acc1[xq] = fmaf(w1, rr[xq+kw], acc1[xq]);
                }
            }
        }
    }
    bool spk0 = false, spk1 = false;
    #pragma unroll
    for (int jj = 0; jj < 2; jj++) {
        int j = j0 + jj;
        if (j < 100) {
            size_t n0 = ((size_t)(b*100 + j)*H2 + y)*H2 + x0;
            bool anyspk = false;
            #pragma unroll
            for (int i = 0; i < 3; i++) {
                float4 v4 = ((const float4*)(v1 + n0))[i];
                float4 c4 = ((const float4*)(i1 + n0))[i];
                float4 t4 = ((const float4*)(tq2 + n0))[i];
                float4 vn, in, zn, tn;
                float* vp=(float*)&v4; float* cp=(float*)&c4; float* tp=(float*)&t4;
                float* vnp=(float*)&vn; float* inp=(float*)&in; float* znp=(float*)&zn; float* tnp=(float*)&tn;
                #pragma unroll
                for (int k = 0; k < 4; k++) {
                    float a = jj ? acc1[i*4+k] : acc0[i*4+k];
                    float vd = vp[k] + DTMEM*(cp[k] - vp[k]);
                    float z = (vd > 10.0f) ? 1.0f : 0.0f;
                    vnp[k] = (1.0f - z)*vd;
                    inp[k] = (cp[k] - DTSYN*cp[k]) + 10.0f*a;
                    znp[k] = z;
                    tnp[k] = tp[k] + DTTR*(z - tp[k]);
                    anyspk = anyspk || (z != 0.f);
                }
                ((float4*)(v1 + n0))[i] = vn;
                ((float4*)(i1 + n0))[i] = in;
                ((float4*)(z4 + n0))[i] = zn;
                ((float4*)(tq2 + n0))[i] = tn;
            }
            if (jj == 0) spk0 = anyspk; else spk1 = anyspk;
        }
    }
    if (spk0) atomicOr(&sjany[jp*2], 1);
    if (spk1) atomicOr(&sjany[jp*2+1], 1);
    __syncthreads();
    if (tid < 8 && jb0 + tid < 100) g_t[b*100 + jb0 + tid] = sjany[tid] ? 1.f : 0.f;
}

// ================= K_C: stdp2 correlation (row-based, jb=2, deterministic) =================
// MODE 0 (E+): pre=tp2, post=z4, skip per-b via g_t flags.
// MODE 1 (E-): pre=z3,  post=tq2, skip per-b via cnz2.
template<int MODE>
__global__ __launch_bounds__(192) void k_corr(
        const float* __restrict__ pre, const float* __restrict__ post,
        float* __restrict__ E, const float* __restrict__ gflag,
        const int* __restrict__ cnz2) {
    __shared__ __attribute__((aligned(16))) float spre[LP];
    __shared__ float sflag[8];
    __shared__ float red[3*200];
    int jg = blockIdx.x, c = blockIdx.y, tid = threadIdx.x;
    int jb0 = jg*8;
    int jp = tid & 3, xh = (tid >> 2) & 1, y = tid >> 3;
    int j0 = jb0 + jp*2, x0 = xh*12;
    int jl0 = (j0 < 100) ? j0 : 99;
    int jl1 = (j0+1 < 100) ? j0+1 : 99;
    float accA[25], accB[25];
    #pragma unroll
    for (int p = 0; p < 25; p++) { accA[p] = 0.f; accB[p] = 0.f; }
    #pragma unroll 1
    for (int b = 0; b < B; b++) {
        __syncthreads();
        if (MODE == 0 && tid < 8)
            sflag[tid] = (jb0 + tid < 100) ? gflag[b*100 + jb0 + tid] : 0.f;
        __syncthreads();
        bool anyb;
        if (MODE == 0)
            anyb = (sflag[0] + sflag[1] + sflag[2] + sflag[3] +
                    sflag[4] + sflag[5] + sflag[6] + sflag[7]) != 0.f;
        else
            anyb = (cnz2[(b*30 + c)*2] | cnz2[(b*30 + c)*2 + 1]) != 0;
        if (anyb) {
            const float4* src = (const float4*)(pre + (size_t)(b*30 + c)*LP);
            float4* dst = (float4*)spre;
            for (int i = tid; i < 196; i += 192) dst[i] = src[i];
        }
        __syncthreads();
        if (!anyb) continue;
        bool mine = true;
        if (MODE == 0) mine = (sflag[jp*2] != 0.f) || (sflag[jp*2+1] != 0.f);
        if (!mine) continue;
        float pA[12], pB[12];
        {
            size_t nA = ((size_t)(b*100 + jl0)*H2 + y)*H2 + x0;
            size_t nB = ((size_t)(b*100 + jl1)*H2 + y)*H2 + x0;
            #pragma unroll
            for (int i = 0; i < 3; i++) {
                ((float4*)pA)[i] = ((const float4*)(post + nA))[i];
                ((float4*)pB)[i] = ((const float4*)(post + nB))[i];
            }
        }
        #pragma unroll
        for (int kh = 0; kh < 5; kh++) {
            float rr[16];
            const float4* r4 = (const float4*)&spre[(y+kh)*HP + x0];
            #pragma unroll
            for (int i = 0; i < 4; i++) ((float4*)rr)[i] = r4[i];
            #pragma unroll
            for (int kw = 0; kw < 5; kw++)
                #pragma unroll
                for (int xq = 0; xq < 12; xq++) {
                    accA[kh*5+kw] = fmaf(rr[xq+kw], pA[xq], accA[kh*5+kw]);
                    accB[kh*5+kw] = fmaf(rr[xq+kw], pB[xq], accB[kh*5+kw]);
                }
        }
    }
    int lane = tid & 63, wave = tid >> 6;
    #pragma unroll
    for (int q = 0; q < 50; q++) {
        float v = (q < 25) ? accA[q] : accB[q-25];
        v += __shfl_xor(v, 4, 64);
        v += __shfl_xor(v, 8, 64);
        v += __shfl_xor(v, 16, 64);
        v += __shfl_xor(v, 32, 64);
        if (lane < 4) red[wave*200 + lane*50 + q] = v;
    }
    __syncthreads();
    if (tid < 200) {
        int jp2 = tid / 50, q = tid % 50;
        float s = red[0*200 + jp2*50 + q] + red[1*200 + jp2*50 + q] + red[2*200 + jp2*50 + q];
        int j = jb0 + jp2*2 + ((q < 25) ? 0 : 1), p = q % 25;
        if (j < 100) E[((size_t)j*30 + c)*25 + p] = s;
    }
}

// ================= k_apply: stdp1 apply + stdp2 apply (also maintains w2p) =================
__global__ void k_apply(float* __restrict__ w1c, const float* __restrict__ part,
                        float* __restrict__ w2c, float* __restrict__ w2p,
                        const float* __restrict__ Ep, const float* __restrict__ Em) {
    int e = blockIdx.x*blockDim.x + threadIdx.x;
    if (e < 1500) {
        int o = e / 50, r = e % 50, ch = r / 25, p = r % 25;
        float EpS = 0.f, EmS = 0.f;
        #pragma unroll
        for (int s = 0; s < 32; s++) {
            EpS += part[((size_t)(o*50 + p) << 5) + s];
            EmS += part[((size_t)(o*50 + 25 + p) << 5) + s];
        }
        float sign = (ch == 0) ? 1.0f : -1.0f;
        float w = w1c[e];
        float dwp = 0.004f * fmaxf(1.0f - w, 0.0f) * (sign * EpS);
        float dwm = 0.003f * fmaxf(w, 0.0f) * (sign * EmS);
        w1c[e] = fminf(fmaxf(w + dwp - dwm, 0.0f), 1.0f);
    } else if (e < 76500) {
        int f = e - 1500;
        float w = w2c[f];
        float dwp = 0.004f * fmaxf(1.0f - w, 0.0f) * Ep[f];
        float dwm = 0.003f * fmaxf(w, 0.0f) * Em[f];
        float wn = fminf(fmaxf(w + dwp - dwm, 0.0f), 1.0f);
        w2c[f] = wn;
        int j = f / 750, r = f % 750, c = r / 25, p = r % 25;
        w2p[((size_t)j*30 + c)*28 + p] = wn;
    }
}

// ================= k_prep: build padded w2p from initial w2 =================
__global__ void k_prep(const float* __restrict__ w2, float* __restrict__ w2p) {
    int e = blockIdx.x*blockDim.x + threadIdx.x;
    if (e < 75000) {
        int j = e / 750, r = e % 750, c = r / 25, p = r % 25;
        w2p[((size_t)j*30 + c)*28 + p] = w2[e];
    }
}

// ================= k_fc1b: batched fc1 over all T (fcw read once) =================
// grid 500 (n), block 256
__global__ __launch_bounds__(256) void k_fc1b(
        const float* __restrict__ g_all, const float* __restrict__ fcw,
        const float* __restrict__ fcb, float* __restrict__ h_all) {
    __shared__ float red[32][4];
    int n = blockIdx.x, tid = threadIdx.x;
    const float4* w4 = (const float4*)(fcw + (size_t)n*3200);
    float4 wreg[4];
    #pragma unroll
    for (int i = 0; i < 4; i++) {
        int k = tid + 256*i;
        if (k < 800) wreg[i] = w4[k];
    }
    float accs[32];
    #pragma unroll
    for (int t = 0; t < 32; t++) accs[t] = 0.f;
    #pragma unroll 1
    for (int t = 0; t < 32; t++) {
        const float4* g4 = (const float4*)(g_all + (size_t)t*3200);
        float a = 0.f;
        #pragma unroll
        for (int i = 0; i < 4; i++) {
            int k = tid + 256*i;
            if (k < 800) {
                float4 gv = g4[k];
                a = fmaf(gv.x, wreg[i].x, a);
                a = fmaf(gv.y, wreg[i].y, a);
                a = fmaf(gv.z, wreg[i].z, a);
                a = fmaf(gv.w, wreg[i].w, a);
            }
        }
        accs[t] = a;
    }
    int lane = tid & 63, wid = tid >> 6;
    #pragma unroll
    for (int t = 0; t < 32; t++) {
        float v = accs[t];
        #pragma unroll
        for (int s = 32; s >= 1; s >>= 1) v += __shfl_down(v, s, 64);
        if (lane == 0) red[t][wid] = v;
    }
    __syncthreads();
    if (tid < 32)
        h_all[(size_t)tid*500 + n] = red[tid][0] + red[tid][1] + red[tid][2] + red[tid][3] + fcb[n];
}

// ================= k_head_all: LIF2 + LI readout, all T in one block =================
__global__ __launch_bounds__(640) void k_head_all(
        const float* __restrict__ h_all, const float* __restrict__ outw,
        float* __restrict__ out) {
    __shared__ float spk[500];
    __shared__ float vout[10];
    int tid = threadIdx.x;
    int wid = tid >> 6, lane = tid & 63;
    float v2r = 0.f, i2r = 0.f;   // per-neuron state (tid<500)
    float vor = 0.f, ior = 0.f;   // per-class state (lane0 of each wave)
    #pragma unroll 1
    for (int t = 0; t < 32; t++) {
        if (tid < 500) {
            float cur = i2r;
            float vd = v2r + DTMEM*(cur - v2r);
            float z = (vd > 1.0f) ? 1.0f : 0.0f;
            v2r = (1.0f - z)*vd;
            i2r = (cur - DTSYN*cur) + h_all[t*500 + tid];
            spk[tid] = z;
        }
        __syncthreads();
        float acc = 0.f;
        for (int n = lane; n < 500; n += 64)
            acc = fmaf(spk[n], outw[wid*500 + n], acc);
        #pragma unroll
        for (int s = 32; s >= 1; s >>= 1) acc += __shfl_down(acc, s, 64);
        if (lane == 0) {
            float ij = ior + acc;
            float vn = vor + DTMEM*(ij - vor);
            ior = ij - DTSYN*ij;
            vor = vn;
            vout[wid] = vn;
        }
        __syncthreads();
        if (tid < 320) out[(size_t)t*320 + tid] = vout[tid % 10];
        __syncthreads();
    }
}

// ---------------- launcher ----------------
extern "C" void kernel_launch(void* const* d_in, const int* in_sizes, int n_in,
                              void* d_out, int out_size, void* d_ws, size_t ws_size,
                              hipStream_t stream) {
    const float* x    = (const float*)d_in[0];
    const float* b1   = (const float*)d_in[1];
    const float* b2   = (const float*)d_in[2];
    const float* w1   = (const float*)d_in[3];
    const float* w2   = (const float*)d_in[4];
    const float* fcw  = (const float*)d_in[5];
    const float* fcb  = (const float*)d_in[6];
    const float* outw = (const float*)d_in[7];
    float* ws  = (float*)d_ws;
    float* out = (float*)d_out;

    DK dk;
    {
        float g1[25], g2[25], s1 = 0.f, s2 = 0.f;
        for (int i = 0; i < 5; i++)
            for (int j = 0; j < 5; j++) {
                float ai = (float)(i - 2), aj = (float)(j - 2);
                float r2 = ai*ai + aj*aj;
                g1[i*5+j] = expf(-r2/2.0f);
                g2[i*5+j] = expf(-r2/8.0f);
                s1 += g1[i*5+j]; s2 += g2[i*5+j];
            }
        for (int k = 0; k < 25; k++) dk.v[k] = g1[k]/s1 - g2[k]/s2;
    }

    hipMemcpyAsync(ws + OW1, w1, 1500*sizeof(float), hipMemcpyDeviceToDevice, stream);
    hipMemcpyAsync(ws + OW2, w2, 75000*sizeof(float), hipMemcpyDeviceToDevice, stream);
    hipMemsetAsync(ws + OV0, 0, (OTOT - OV0)*sizeof(float), stream);
    k_prep<<<294, 256, 0, stream>>>(ws + OW2, ws + OW2P);

    for (int t = 0; t < T; t++) {
        const float* tp1r = ws + ((t & 1) ? OTP1B : OTP1A);
        float*       tp1w = ws + ((t & 1) ? OTP1A : OTP1B);
        k_front<<<dim3(8, 32), 448, 0, stream>>>(
            x, b1, b2, ws+OW1, tp1r, tp1w, ws+OV0, ws+OI0, ws+OTQ1,
            ws+OZ3, ws+OTP2, ws+OP1, (int*)(ws+OCNZ), dk, t);
        k_conv2lif<<<dim3(13, 32), 192, 0, stream>>>(
            ws+OW2P, ws+OZ3, (int*)(ws+OCNZ),
            ws+OV1, ws+OI1, ws+OZ4, ws+OTQ2, ws+OG + (size_t)t*3200);
        k_corr<0><<<dim3(13, 30), 192, 0, stream>>>(
            ws+OTP2, ws+OZ4, ws+OE2P, ws+OG + (size_t)t*3200, (int*)(ws+OCNZ));
        k_corr<1><<<dim3(13, 30), 192, 0, stream>>>(
            ws+OZ3, ws+OTQ2, ws+OE2M, ws+OG + (size_t)t*3200, (int*)(ws+OCNZ));
        k_apply<<<300, 256, 0, stream>>>(
            ws+OW1, ws+OP1, ws+OW2, ws+OW2P, ws+OE2P, ws+OE2M);
    }
    k_fc1b<<<500, 256, 0, stream>>>(ws+OG, fcw, fcb, ws+OHH);
    k_head_all<<<1, 640, 0, stream>>>(ws+OHH, outw, out);
}